// Round 17
// baseline (122.696 us; speedup 1.0000x reference)
//
#include <hip/hip_runtime.h>

#define Bn 256
#define Nn 64
#define Tn 50
#define Fn 2
#define En 64
#define Hn 128
#define Rn 30
#define G4 512
#define EMS 6416   // emb_lds byte stride per batch row (3208 halves)

typedef _Float16 h2    __attribute__((ext_vector_type(2)));
typedef _Float16 f16x8 __attribute__((ext_vector_type(8)));
typedef float    f32x4 __attribute__((ext_vector_type(4)));

__device__ __forceinline__ float sigf(float x) {
    return __builtin_amdgcn_rcpf(1.0f + __expf(-x));
}
__device__ __forceinline__ float tanh_fast(float x) {
    return 1.0f - 2.0f * __builtin_amdgcn_rcpf(__expf(2.0f * x) + 1.0f);
}
__device__ __forceinline__ h2 pack2(float a, float b) {
    h2 r; r[0] = (_Float16)a; r[1] = (_Float16)b; return r;
}

// lgkm-only barrier (no vmcnt drain)
__device__ __forceinline__ void blockbar() {
    __builtin_amdgcn_sched_barrier(0);
    asm volatile("s_waitcnt lgkmcnt(0)" ::: "memory");
    __builtin_amdgcn_s_barrier();
    __builtin_amdgcn_sched_barrier(0);
}

// ---------------- fused kernel ----------------
// bids 0..63  : seq role (group g = bid, batches [4g,4g+4)). Emb-independent
//               weight prologue (~3 us) overlaps the emb phase, then
//               acquire-spins on ctr[g] (target 4).
// bids 64..319: emb role, one block per batch b = bid-64. Coalesced LDS
//               staging (R16 v2 body) fixes R15's fetch amplification; 256
//               blocks at 1/CU on the 192 free CUs = ~1.4 rounds (~5-6 us)
//               fixes R15's dispatch-round explosion. Releases ctr[b>>2].
// Protocol (release: syncthreads-drain + fence + atomicAdd; acquire: spin +
// fence + syncthreads) carried verbatim from R15, which passed validation.
__global__ __launch_bounds__(512) void k_fused(
    const float* __restrict__ src,
    const float* __restrict__ W_res,  const float* __restrict__ W_gcn,
    const float* __restrict__ b_gcn,
    const float* __restrict__ W_hh_e, const float* __restrict__ W_ih_e,
    const float* __restrict__ b_e,
    const float* __restrict__ W1,     const float* __restrict__ b1,
    const float* __restrict__ W_ih_d, const float* __restrict__ W_hh_d,
    const float* __restrict__ b_d,
    const float* __restrict__ W2,     const float* __restrict__ b2,
    unsigned int* __restrict__ ctr,
    _Float16* __restrict__ emb,
    float* __restrict__ out)
{
    const int tid  = threadIdx.x;
    const int lane = tid & 63;
    const int wv   = tid >> 6;          // 0..7

    __shared__ __align__(16) _Float16 hbuf[2][576];            // 4 rows x 288B stride
    __shared__ __align__(16) _Float16 wi_frag[8 * 8 * 64 * 8]; // 64 KB
    __shared__ __align__(16) _Float16 emb_lds[4 * 3208];       // 25.1 KB padded
    __shared__ __align__(16) float    redw[2][8][4][2];

    // ================= emb role: one block per batch =================
    if (blockIdx.x >= 64) {
        const int bb = blockIdx.x - 64;

        float2* xt = reinterpret_cast<float2*>(&wi_frag[0]);   // 26 KB of 64 KB
        const float2* s2 = reinterpret_cast<const float2*>(src + (size_t)bb * Nn * Tn * Fn);
        for (int i = tid; i < Nn * Tn; i += 512) {
            const int n = i / Tn;
            const int t = i - n * Tn;
            xt[t * 65 + n] = s2[i];    // coalesced read, 2-way-aliased write (free)
        }

        const float wg0 = W_gcn[lane], wg1 = W_gcn[En + lane];
        const float wr0 = W_res[lane], wr1 = W_res[En + lane];
        const float bg  = b_gcn[lane];
        __syncthreads();

        for (int t = wv; t < Tn; t += 8) {
            const float2* row = &xt[t * 65];
            const float2 xv = row[lane];
            const float x0 = xv.x, x1 = xv.y;

            float rowsum = 0.0f, w0 = 0.0f;
            #pragma unroll
            for (int k = 0; k < Nn; k++) {
                const float2 o = row[k];   // broadcast
                const float dx = x0 - o.x, dy = x1 - o.y;
                const float w = fminf(__builtin_amdgcn_rsqf(dx * dx + dy * dy), 1.0f);
                rowsum += w;
                if (k == 0) w0 = w;
            }
            const float dinv  = __builtin_amdgcn_rsqf(rowsum);
            const float dinv0 = __shfl(dinv, 0);
            const float a = w0 * dinv0 * dinv;     // A[0, lane]

            float p0 = a * x0, p1 = a * x1;
            #pragma unroll
            for (int off = 32; off; off >>= 1) {
                p0 += __shfl_xor(p0, off);
                p1 += __shfl_xor(p1, off);
            }
            const float xa = __shfl(x0, 0);
            const float xb = __shfl(x1, 0);

            const float v = p0 * wg0 + p1 * wg1 + bg + xa * wr0 + xb * wr1;
            emb[((size_t)bb * Tn + t) * En + lane] = (_Float16)fmaxf(v, 0.0f);
        }

        __syncthreads();                   // each wave drains vmcnt before barrier
        if (tid == 0) {
            __threadfence();               // device-visible
            atomicAdd(&ctr[bb >> 2], 1u);  // release: 4 batches per seq group
        }
        return;
    }

    // ================= seq role (R13 body, verified 77.6 us) =================
    const int l15  = lane & 15;
    const int lg   = lane >> 4;         // 0..3 : k-subgroup AND owned batch
    const int cc   = wv * 16 + l15;     // owned cell column 0..127
    const int g    = blockIdx.x;
    const int bq0  = g * 4;
    const int mb   = l15 & 3;           // batch of this lane's A-rows

    char* const embbase = reinterpret_cast<char*>(&emb_lds[0]);

    // ---- emb-independent prologue: encoder W_hh_e B-fragments ----
    f16x8 bfr[4][4];
    #pragma unroll
    for (int gg = 0; gg < 4; gg++)
        #pragma unroll
        for (int kt = 0; kt < 4; kt++) {
            f16x8 v;
            #pragma unroll
            for (int j = 0; j < 8; j++)
                v[j] = (_Float16)W_hh_e[(size_t)(kt * 32 + lg * 8 + j) * G4 + gg * 128 + cc];
            bfr[gg][kt] = v;
        }

    // ---- W_ih_e fragments -> wi_frag ----
    #pragma unroll
    for (int gg = 0; gg < 4; gg++)
        #pragma unroll
        for (int kt2 = 0; kt2 < 2; kt2++) {
            f16x8 v;
            #pragma unroll
            for (int j = 0; j < 8; j++)
                v[j] = (_Float16)W_ih_e[(size_t)(kt2 * 32 + lg * 8 + j) * G4 + gg * 128 + cc];
            *reinterpret_cast<f16x8*>(&wi_frag[((wv * 8 + gg * 2 + kt2) * 64 + lane) * 8]) = v;
        }

    if (tid < 288) reinterpret_cast<float*>(&hbuf[0][0])[tid] = 0.0f;

    const float be0 = b_e[cc], be1 = b_e[128 + cc], be2 = b_e[256 + cc], be3 = b_e[384 + cc];

    // ---- acquire this group's 4 emb batches ----
    if (tid == 0) {
        while (atomicAdd(&ctr[g], 0u) < 4u) __builtin_amdgcn_s_sleep(2);
        __threadfence();
    }
    __syncthreads();

    // ---- stage emb rows for the 4 owned batches ----
    {
        const _Float16* eg = emb + (size_t)bq0 * Tn * En;
        for (int i = tid; i < 1600; i += 512) {
            const int m = i / 400;
            const int r = i - m * 400;
            const uint4 v = *reinterpret_cast<const uint4*>(eg + i * 8);
            *reinterpret_cast<uint4*>(embbase + m * EMS + r * 16) = v;
        }
    }

    float cst = 0.0f;
    char* const hb0 = reinterpret_cast<char*>(&hbuf[0][0]);
    char* const hb1 = reinterpret_cast<char*>(&hbuf[1][0]);
    const int afo = (l15 & 3) * 288 + lg * 16;
    const int aeo = mb * EMS + lg * 16;
    const int hwo = lg * 288 + cc * 2;
    __syncthreads();

    // ---- encoder: 50 steps, 1 barrier/step, zero global loads ----
    for (int t = 0; t < Tn; t++) {
        const int cur = t & 1;
        char* const hr = cur ? hb1 : hb0;
        char* const hw = cur ? hb0 : hb1;

        f16x8 af[4];
        #pragma unroll
        for (int kt = 0; kt < 4; kt++)
            af[kt] = *reinterpret_cast<const f16x8*>(hr + afo + kt * 64);
        f16x8 ae[2];
        #pragma unroll
        for (int kt2 = 0; kt2 < 2; kt2++)
            ae[kt2] = *reinterpret_cast<const f16x8*>(embbase + aeo + t * 128 + kt2 * 64);

        f32x4 acc[4] = {};
        #pragma unroll
        for (int kt = 0; kt < 4; kt++)
            #pragma unroll
            for (int gg = 0; gg < 4; gg++)
                acc[gg] = __builtin_amdgcn_mfma_f32_16x16x32_f16(af[kt], bfr[gg][kt], acc[gg], 0, 0, 0);
        #pragma unroll
        for (int gg = 0; gg < 4; gg++)
            #pragma unroll
            for (int kt2 = 0; kt2 < 2; kt2++) {
                const f16x8 bfe = *reinterpret_cast<const f16x8*>(
                    &wi_frag[((wv * 8 + gg * 2 + kt2) * 64 + lane) * 8]);
                acc[gg] = __builtin_amdgcn_mfma_f32_16x16x32_f16(ae[kt2], bfe, acc[gg], 0, 0, 0);
            }

        float ga[4];
        #pragma unroll
        for (int gg = 0; gg < 4; gg++) {
            const float s01 = (lg & 1) ? acc[gg][1] : acc[gg][0];
            const float s23 = (lg & 1) ? acc[gg][3] : acc[gg][2];
            ga[gg] = (lg & 2) ? s23 : s01;
        }

        const float gi = ga[0] + be0;
        const float gf = ga[1] + be1;
        const float gG = ga[2] + be2;
        const float go = ga[3] + be3;
        cst = sigf(gf) * cst + sigf(gi) * tanh_fast(gG);
        const float hv = sigf(go) * tanh_fast(cst);

        *reinterpret_cast<_Float16*>(hw + hwo) = (_Float16)hv;
        blockbar();
    }

    // ---- decoder setup: reload bfr + wi_frag with decoder weights ----
    #pragma unroll
    for (int gg = 0; gg < 4; gg++)
        #pragma unroll
        for (int kt = 0; kt < 4; kt++) {
            f16x8 v;
            #pragma unroll
            for (int j = 0; j < 8; j++)
                v[j] = (_Float16)W_hh_d[(size_t)(kt * 32 + lg * 8 + j) * G4 + gg * 128 + cc];
            bfr[gg][kt] = v;
        }
    #pragma unroll
    for (int gg = 0; gg < 4; gg++)
        #pragma unroll
        for (int kt2 = 0; kt2 < 2; kt2++) {
            f16x8 v;
            #pragma unroll
            for (int j = 0; j < 8; j++)
                v[j] = (_Float16)W_ih_d[(size_t)(kt2 * 32 + lg * 8 + j) * G4 + gg * 128 + cc];
            *reinterpret_cast<f16x8*>(&wi_frag[((wv * 8 + gg * 2 + kt2) * 64 + lane) * 8]) = v;
        }

    const float bd0 = b_d[cc], bd1 = b_d[128 + cc], bd2 = b_d[256 + cc], bd3 = b_d[384 + cc];
    const float w2a = W2[cc * 2], w2b = W2[cc * 2 + 1];
    const float b20 = b2[0], b21 = b2[1];

    // W1/b1 packed consts for in-register ED (verified R12)
    h2 w1ah[8], w1bh[8], b1h[8];
    #pragma unroll
    for (int q = 0; q < 8; q++) {
        const int e0 = (q >> 2) * 32 + lg * 8 + (q & 3) * 2;
        w1ah[q] = pack2(W1[e0],      W1[e0 + 1]);
        w1bh[q] = pack2(W1[En + e0], W1[En + e0 + 1]);
        b1h[q]  = pack2(b1[e0],      b1[e0 + 1]);
    }

    float o0 = src[((size_t)(bq0 + mb) * Nn * Tn + (Tn - 1)) * Fn + 0];
    float o1 = src[((size_t)(bq0 + mb) * Nn * Tn + (Tn - 1)) * Fn + 1];
    __syncthreads();   // wi_frag reload visibility

    // ---- decoder: 30 steps, 1 barrier/step ----
    for (int r = 0; r < Rn; r++) {
        const int cur = r & 1;
        char* const hr = cur ? hb1 : hb0;
        char* const hw = cur ? hb0 : hb1;

        const h2 o0h = pack2(o0, o0);
        const h2 o1h = pack2(o1, o1);
        f16x8 ae[2];
        #pragma unroll
        for (int kt2 = 0; kt2 < 2; kt2++)
            #pragma unroll
            for (int p = 0; p < 4; p++) {
                h2 v = w1ah[kt2 * 4 + p] * o0h + w1bh[kt2 * 4 + p] * o1h + b1h[kt2 * 4 + p];
                v[0] = v[0] > (_Float16)0 ? v[0] : (_Float16)0;
                v[1] = v[1] > (_Float16)0 ? v[1] : (_Float16)0;
                ae[kt2][2 * p]     = v[0];
                ae[kt2][2 * p + 1] = v[1];
            }

        f16x8 af[4];
        #pragma unroll
        for (int kt = 0; kt < 4; kt++)
            af[kt] = *reinterpret_cast<const f16x8*>(hr + afo + kt * 64);

        f32x4 acc[4] = {};
        #pragma unroll
        for (int kt = 0; kt < 4; kt++)
            #pragma unroll
            for (int gg = 0; gg < 4; gg++)
                acc[gg] = __builtin_amdgcn_mfma_f32_16x16x32_f16(af[kt], bfr[gg][kt], acc[gg], 0, 0, 0);
        #pragma unroll
        for (int gg = 0; gg < 4; gg++)
            #pragma unroll
            for (int kt2 = 0; kt2 < 2; kt2++) {
                const f16x8 bfe = *reinterpret_cast<const f16x8*>(
                    &wi_frag[((wv * 8 + gg * 2 + kt2) * 64 + lane) * 8]);
                acc[gg] = __builtin_amdgcn_mfma_f32_16x16x32_f16(ae[kt2], bfe, acc[gg], 0, 0, 0);
            }

        float ga[4];
        #pragma unroll
        for (int gg = 0; gg < 4; gg++) {
            const float s01 = (lg & 1) ? acc[gg][1] : acc[gg][0];
            const float s23 = (lg & 1) ? acc[gg][3] : acc[gg][2];
            ga[gg] = (lg & 2) ? s23 : s01;
        }

        const float gi = ga[0] + bd0;
        const float gf = ga[1] + bd1;
        const float gG = ga[2] + bd2;
        const float go = ga[3] + bd3;
        cst = sigf(gf) * cst + sigf(gi) * tanh_fast(gG);
        const float hv = sigf(go) * tanh_fast(cst);
        *reinterpret_cast<_Float16*>(hw + hwo) = (_Float16)hv;

        float p0 = hv * w2a, p1 = hv * w2b;
        #pragma unroll
        for (int off = 1; off < 16; off <<= 1) {
            p0 += __shfl_xor(p0, off);
            p1 += __shfl_xor(p1, off);
        }
        if (l15 == 0) {
            redw[cur][wv][lg][0] = p0;
            redw[cur][wv][lg][1] = p1;
        }
        blockbar();

        o0 = b20; o1 = b21;
        #pragma unroll
        for (int w8 = 0; w8 < 8; w8++) {
            const float2 rr = *reinterpret_cast<const float2*>(&redw[cur][w8][mb][0]);
            o0 += rr.x; o1 += rr.y;
        }
        if (wv == 4 && l15 < 2) {
            float oo = l15 ? b21 : b20;
            #pragma unroll
            for (int w8 = 0; w8 < 8; w8++) oo += redw[cur][w8][lg][l15];
            out[(((size_t)(bq0 + lg)) * Rn + r) * Fn + l15] = oo;
        }
    }
}

extern "C" void kernel_launch(void* const* d_in, const int* in_sizes, int n_in,
                              void* d_out, int out_size, void* d_ws, size_t ws_size,
                              hipStream_t stream)
{
    const float* src    = (const float*)d_in[0];
    const float* W_res  = (const float*)d_in[2];
    const float* W_gcn  = (const float*)d_in[3];
    const float* b_gcn  = (const float*)d_in[4];
    const float* W_ih_e = (const float*)d_in[5];
    const float* W_hh_e = (const float*)d_in[6];
    const float* b_e    = (const float*)d_in[7];
    const float* W1     = (const float*)d_in[8];
    const float* b1     = (const float*)d_in[9];
    const float* W_ih_d = (const float*)d_in[10];
    const float* W_hh_d = (const float*)d_in[11];
    const float* b_d    = (const float*)d_in[12];
    const float* W2     = (const float*)d_in[13];
    const float* b2     = (const float*)d_in[14];

    float* out = (float*)d_out;
    unsigned int* ctr = (unsigned int*)d_ws;                       // 64 group counters
    _Float16* emb = (_Float16*)((char*)d_ws + 256);                // 12800x64 fp16

    hipMemsetAsync(d_ws, 0, 256, stream);                          // zero counters each call
    k_fused<<<64 + Bn, 512, 0, stream>>>(
        src, W_res, W_gcn, b_gcn,
        W_hh_e, W_ih_e, b_e,
        W1, b1,
        W_ih_d, W_hh_d, b_d,
        W2, b2,
        ctr, emb, out);
}

// Round 18
// 90.329 us; speedup vs baseline: 1.3583x; 1.3583x over previous
//
#include <hip/hip_runtime.h>

#define Bn 256
#define Nn 64
#define Tn 50
#define Fn 2
#define En 64
#define Hn 128
#define Rn 30
#define G4 512
#define EMS 6416   // emb_lds byte stride per batch row (3208 halves)

typedef _Float16 h2    __attribute__((ext_vector_type(2)));
typedef _Float16 f16x8 __attribute__((ext_vector_type(8)));
typedef float    f32x4 __attribute__((ext_vector_type(4)));

__device__ __forceinline__ float sigf(float x) {
    return __builtin_amdgcn_rcpf(1.0f + __expf(-x));
}
__device__ __forceinline__ float tanh_fast(float x) {
    return 1.0f - 2.0f * __builtin_amdgcn_rcpf(__expf(2.0f * x) + 1.0f);
}
__device__ __forceinline__ h2 pack2(float a, float b) {
    h2 r; r[0] = (_Float16)a; r[1] = (_Float16)b; return r;
}

// lgkm-only barrier (no vmcnt drain)
__device__ __forceinline__ void blockbar() {
    __builtin_amdgcn_sched_barrier(0);
    asm volatile("s_waitcnt lgkmcnt(0)" ::: "memory");
    __builtin_amdgcn_s_barrier();
    __builtin_amdgcn_sched_barrier(0);
}

// ---------------- k_emb: GCN + residual + relu at node 0 -> emb fp16[12800][64] ----------------
// 1600 blocks x 8 waves, 1 task (b,t) per wave; lane = node. (R13 config —
// measured best; R16's coalesced variant was neutral, fusion (R15/R17) lost
// to union-LDS occupancy collapse.)
__global__ __launch_bounds__(512) void k_emb(const float* __restrict__ src,
                                             const float* __restrict__ W_res,
                                             const float* __restrict__ W_gcn,
                                             const float* __restrict__ b_gcn,
                                             _Float16* __restrict__ emb)
{
    const int lane = threadIdx.x & 63;
    const int wv   = threadIdx.x >> 6;
    const int task = blockIdx.x * 8 + wv;
    const int b = task / Tn;
    const int t = task - b * Tn;

    __shared__ float2 xs[8][Nn];

    const float2 xv = *reinterpret_cast<const float2*>(
        src + (((size_t)b * Nn + lane) * Tn + t) * Fn);
    const float x0 = xv.x, x1 = xv.y;
    xs[wv][lane] = xv;

    float rowsum = 0.0f, w0 = 0.0f;
    #pragma unroll
    for (int k = 0; k < Nn; k++) {
        const float2 o = xs[wv][k];
        const float dx = x0 - o.x, dy = x1 - o.y;
        const float w = fminf(__builtin_amdgcn_rsqf(dx * dx + dy * dy), 1.0f);
        rowsum += w;
        if (k == 0) w0 = w;
    }
    const float dinv  = __builtin_amdgcn_rsqf(rowsum);
    const float dinv0 = __shfl(dinv, 0);
    const float a = w0 * dinv0 * dinv;     // A[0, lane]

    float p0 = a * x0, p1 = a * x1;
    #pragma unroll
    for (int off = 32; off; off >>= 1) {
        p0 += __shfl_xor(p0, off);
        p1 += __shfl_xor(p1, off);
    }
    const float xa = __shfl(x0, 0);
    const float xb = __shfl(x1, 0);

    const float v = p0 * W_gcn[lane] + p1 * W_gcn[En + lane] + b_gcn[lane]
                  + xa * W_res[lane] + xb * W_res[En + lane];
    emb[(size_t)task * En + lane] = (_Float16)fmaxf(v, 0.0f);
}

// ---------------- k_seq: M=4 replicated-A MFMA LSTM (verified best: 77.6 us) ----------------
// 64 blocks x 512 thr; block owns 4 batches (MFMA M via replicated A rows).
// Wave wv owns cells [16wv,16wv+16); lane (l15,lg) owns cell (batch lg,
// col 16wv+l15) with gates i/f/g/o all in-register after MFMA. Encoder:
// 24 MFMA/step (h@W_hh_e + emb_t@W_ih_e), 1 barrier/step, zero global
// loads. Decoder: in-register ED from (o0,o1), 1 barrier/step.
__global__ __launch_bounds__(512) void k_seq(
    const _Float16* __restrict__ emb,
    const float* __restrict__ src,
    const float* __restrict__ W_hh_e, const float* __restrict__ W_ih_e,
    const float* __restrict__ b_e,
    const float* __restrict__ W1,     const float* __restrict__ b1,
    const float* __restrict__ W_ih_d, const float* __restrict__ W_hh_d,
    const float* __restrict__ b_d,
    const float* __restrict__ W2,     const float* __restrict__ b2,
    float* __restrict__ out)
{
    const int tid  = threadIdx.x;
    const int lane = tid & 63;
    const int wv   = tid >> 6;          // 0..7
    const int l15  = lane & 15;
    const int lg   = lane >> 4;         // 0..3 : k-subgroup AND owned batch
    const int cc   = wv * 16 + l15;     // owned cell column 0..127
    const int bq0  = blockIdx.x * 4;
    const int mb   = l15 & 3;           // batch of this lane's A-rows

    __shared__ __align__(16) _Float16 hbuf[2][576];            // 4 rows x 288B stride
    __shared__ __align__(16) _Float16 wi_frag[8 * 8 * 64 * 8]; // 64 KB
    __shared__ __align__(16) _Float16 emb_lds[4 * 3208];       // 25.1 KB padded
    __shared__ __align__(16) float    redw[2][8][4][2];

    char* const embbase = reinterpret_cast<char*>(&emb_lds[0]);

    // ---- encoder W_hh_e B-fragments (verified layout) ----
    f16x8 bfr[4][4];
    #pragma unroll
    for (int g = 0; g < 4; g++)
        #pragma unroll
        for (int kt = 0; kt < 4; kt++) {
            f16x8 v;
            #pragma unroll
            for (int j = 0; j < 8; j++)
                v[j] = (_Float16)W_hh_e[(size_t)(kt * 32 + lg * 8 + j) * G4 + g * 128 + cc];
            bfr[g][kt] = v;
        }

    // ---- W_ih_e fragments -> wi_frag ----
    #pragma unroll
    for (int g = 0; g < 4; g++)
        #pragma unroll
        for (int kt2 = 0; kt2 < 2; kt2++) {
            f16x8 v;
            #pragma unroll
            for (int j = 0; j < 8; j++)
                v[j] = (_Float16)W_ih_e[(size_t)(kt2 * 32 + lg * 8 + j) * G4 + g * 128 + cc];
            *reinterpret_cast<f16x8*>(&wi_frag[((wv * 8 + g * 2 + kt2) * 64 + lane) * 8]) = v;
        }

    // ---- stage emb rows for the 4 owned batches ----
    {
        const _Float16* eg = emb + (size_t)bq0 * Tn * En;
        for (int i = tid; i < 1600; i += 512) {
            const int m = i / 400;
            const int r = i - m * 400;
            const uint4 v = *reinterpret_cast<const uint4*>(eg + i * 8);
            *reinterpret_cast<uint4*>(embbase + m * EMS + r * 16) = v;
        }
    }

    if (tid < 288) reinterpret_cast<float*>(&hbuf[0][0])[tid] = 0.0f;

    const float be0 = b_e[cc], be1 = b_e[128 + cc], be2 = b_e[256 + cc], be3 = b_e[384 + cc];

    float cst = 0.0f;
    char* const hb0 = reinterpret_cast<char*>(&hbuf[0][0]);
    char* const hb1 = reinterpret_cast<char*>(&hbuf[1][0]);
    const int afo = (l15 & 3) * 288 + lg * 16;
    const int aeo = mb * EMS + lg * 16;
    const int hwo = lg * 288 + cc * 2;
    __syncthreads();

    // ---- encoder: 50 steps, 1 barrier/step, zero global loads ----
    for (int t = 0; t < Tn; t++) {
        const int cur = t & 1;
        char* const hr = cur ? hb1 : hb0;
        char* const hw = cur ? hb0 : hb1;

        f16x8 af[4];
        #pragma unroll
        for (int kt = 0; kt < 4; kt++)
            af[kt] = *reinterpret_cast<const f16x8*>(hr + afo + kt * 64);
        f16x8 ae[2];
        #pragma unroll
        for (int kt2 = 0; kt2 < 2; kt2++)
            ae[kt2] = *reinterpret_cast<const f16x8*>(embbase + aeo + t * 128 + kt2 * 64);

        f32x4 acc[4] = {};
        #pragma unroll
        for (int kt = 0; kt < 4; kt++)
            #pragma unroll
            for (int g = 0; g < 4; g++)
                acc[g] = __builtin_amdgcn_mfma_f32_16x16x32_f16(af[kt], bfr[g][kt], acc[g], 0, 0, 0);
        #pragma unroll
        for (int g = 0; g < 4; g++)
            #pragma unroll
            for (int kt2 = 0; kt2 < 2; kt2++) {
                const f16x8 bfe = *reinterpret_cast<const f16x8*>(
                    &wi_frag[((wv * 8 + g * 2 + kt2) * 64 + lane) * 8]);
                acc[g] = __builtin_amdgcn_mfma_f32_16x16x32_f16(ae[kt2], bfe, acc[g], 0, 0, 0);
            }

        float ga[4];
        #pragma unroll
        for (int g = 0; g < 4; g++) {
            const float s01 = (lg & 1) ? acc[g][1] : acc[g][0];
            const float s23 = (lg & 1) ? acc[g][3] : acc[g][2];
            ga[g] = (lg & 2) ? s23 : s01;
        }

        const float gi = ga[0] + be0;
        const float gf = ga[1] + be1;
        const float gg = ga[2] + be2;
        const float go = ga[3] + be3;
        cst = sigf(gf) * cst + sigf(gi) * tanh_fast(gg);
        const float hv = sigf(go) * tanh_fast(cst);

        *reinterpret_cast<_Float16*>(hw + hwo) = (_Float16)hv;
        blockbar();
    }

    // ---- decoder setup: reload bfr + wi_frag with decoder weights ----
    #pragma unroll
    for (int g = 0; g < 4; g++)
        #pragma unroll
        for (int kt = 0; kt < 4; kt++) {
            f16x8 v;
            #pragma unroll
            for (int j = 0; j < 8; j++)
                v[j] = (_Float16)W_hh_d[(size_t)(kt * 32 + lg * 8 + j) * G4 + g * 128 + cc];
            bfr[g][kt] = v;
        }
    #pragma unroll
    for (int g = 0; g < 4; g++)
        #pragma unroll
        for (int kt2 = 0; kt2 < 2; kt2++) {
            f16x8 v;
            #pragma unroll
            for (int j = 0; j < 8; j++)
                v[j] = (_Float16)W_ih_d[(size_t)(kt2 * 32 + lg * 8 + j) * G4 + g * 128 + cc];
            *reinterpret_cast<f16x8*>(&wi_frag[((wv * 8 + g * 2 + kt2) * 64 + lane) * 8]) = v;
        }

    const float bd0 = b_d[cc], bd1 = b_d[128 + cc], bd2 = b_d[256 + cc], bd3 = b_d[384 + cc];
    const float w2a = W2[cc * 2], w2b = W2[cc * 2 + 1];
    const float b20 = b2[0], b21 = b2[1];

    // W1/b1 packed consts for in-register ED (verified R12)
    h2 w1ah[8], w1bh[8], b1h[8];
    #pragma unroll
    for (int q = 0; q < 8; q++) {
        const int e0 = (q >> 2) * 32 + lg * 8 + (q & 3) * 2;
        w1ah[q] = pack2(W1[e0],      W1[e0 + 1]);
        w1bh[q] = pack2(W1[En + e0], W1[En + e0 + 1]);
        b1h[q]  = pack2(b1[e0],      b1[e0 + 1]);
    }

    float o0 = src[((size_t)(bq0 + mb) * Nn * Tn + (Tn - 1)) * Fn + 0];
    float o1 = src[((size_t)(bq0 + mb) * Nn * Tn + (Tn - 1)) * Fn + 1];
    __syncthreads();   // wi_frag reload visibility

    // ---- decoder: 30 steps, 1 barrier/step ----
    for (int r = 0; r < Rn; r++) {
        const int cur = r & 1;
        char* const hr = cur ? hb1 : hb0;
        char* const hw = cur ? hb0 : hb1;

        const h2 o0h = pack2(o0, o0);
        const h2 o1h = pack2(o1, o1);
        f16x8 ae[2];
        #pragma unroll
        for (int kt2 = 0; kt2 < 2; kt2++)
            #pragma unroll
            for (int p = 0; p < 4; p++) {
                h2 v = w1ah[kt2 * 4 + p] * o0h + w1bh[kt2 * 4 + p] * o1h + b1h[kt2 * 4 + p];
                v[0] = v[0] > (_Float16)0 ? v[0] : (_Float16)0;
                v[1] = v[1] > (_Float16)0 ? v[1] : (_Float16)0;
                ae[kt2][2 * p]     = v[0];
                ae[kt2][2 * p + 1] = v[1];
            }

        f16x8 af[4];
        #pragma unroll
        for (int kt = 0; kt < 4; kt++)
            af[kt] = *reinterpret_cast<const f16x8*>(hr + afo + kt * 64);

        f32x4 acc[4] = {};
        #pragma unroll
        for (int kt = 0; kt < 4; kt++)
            #pragma unroll
            for (int g = 0; g < 4; g++)
                acc[g] = __builtin_amdgcn_mfma_f32_16x16x32_f16(af[kt], bfr[g][kt], acc[g], 0, 0, 0);
        #pragma unroll
        for (int g = 0; g < 4; g++)
            #pragma unroll
            for (int kt2 = 0; kt2 < 2; kt2++) {
                const f16x8 bfe = *reinterpret_cast<const f16x8*>(
                    &wi_frag[((wv * 8 + g * 2 + kt2) * 64 + lane) * 8]);
                acc[g] = __builtin_amdgcn_mfma_f32_16x16x32_f16(ae[kt2], bfe, acc[g], 0, 0, 0);
            }

        float ga[4];
        #pragma unroll
        for (int g = 0; g < 4; g++) {
            const float s01 = (lg & 1) ? acc[g][1] : acc[g][0];
            const float s23 = (lg & 1) ? acc[g][3] : acc[g][2];
            ga[g] = (lg & 2) ? s23 : s01;
        }

        const float gi = ga[0] + bd0;
        const float gf = ga[1] + bd1;
        const float gg = ga[2] + bd2;
        const float go = ga[3] + bd3;
        cst = sigf(gf) * cst + sigf(gi) * tanh_fast(gg);
        const float hv = sigf(go) * tanh_fast(cst);
        *reinterpret_cast<_Float16*>(hw + hwo) = (_Float16)hv;

        float p0 = hv * w2a, p1 = hv * w2b;
        #pragma unroll
        for (int off = 1; off < 16; off <<= 1) {
            p0 += __shfl_xor(p0, off);
            p1 += __shfl_xor(p1, off);
        }
        if (l15 == 0) {
            redw[cur][wv][lg][0] = p0;
            redw[cur][wv][lg][1] = p1;
        }
        blockbar();

        o0 = b20; o1 = b21;
        #pragma unroll
        for (int w8 = 0; w8 < 8; w8++) {
            const float2 rr = *reinterpret_cast<const float2*>(&redw[cur][w8][mb][0]);
            o0 += rr.x; o1 += rr.y;
        }
        if (wv == 4 && l15 < 2) {
            float oo = l15 ? b21 : b20;
            #pragma unroll
            for (int w8 = 0; w8 < 8; w8++) oo += redw[cur][w8][lg][l15];
            out[(((size_t)(bq0 + lg)) * Rn + r) * Fn + l15] = oo;
        }
    }
}

extern "C" void kernel_launch(void* const* d_in, const int* in_sizes, int n_in,
                              void* d_out, int out_size, void* d_ws, size_t ws_size,
                              hipStream_t stream)
{
    const float* src    = (const float*)d_in[0];
    const float* W_res  = (const float*)d_in[2];
    const float* W_gcn  = (const float*)d_in[3];
    const float* b_gcn  = (const float*)d_in[4];
    const float* W_ih_e = (const float*)d_in[5];
    const float* W_hh_e = (const float*)d_in[6];
    const float* b_e    = (const float*)d_in[7];
    const float* W1     = (const float*)d_in[8];
    const float* b1     = (const float*)d_in[9];
    const float* W_ih_d = (const float*)d_in[10];
    const float* W_hh_d = (const float*)d_in[11];
    const float* b_d    = (const float*)d_in[12];
    const float* W2     = (const float*)d_in[13];
    const float* b2     = (const float*)d_in[14];

    float* out = (float*)d_out;
    _Float16* emb = (_Float16*)d_ws;   // 12800 x 64 fp16 = 1.64 MB scratch

    k_emb<<<(Bn * Tn) / 8, 512, 0, stream>>>(src, W_res, W_gcn, b_gcn, emb);
    k_seq<<<Bn / 4, 512, 0, stream>>>(emb, src,
                                      W_hh_e, W_ih_e, b_e,
                                      W1, b1,
                                      W_ih_d, W_hh_d, b_d,
                                      W2, b2, out);
}